// Round 3
// baseline (245.636 us; speedup 1.0000x reference)
//
#include <hip/hip_runtime.h>
#include <stdint.h>

// ---------------------------------------------------------------------------
// CausalSelfAttention (T=4096, DIM=1024, 16 heads x 64) on gfx950, bf16 MFMA.
// Pipeline: cast->bf16 | rope tables | GEMM1 qkv | fuse(vmix,rms,rope) |
//           transpose V | flash attention (swapped 32x32, in-reg softmax) |
//           GEMM2 -> fp32 out
// ---------------------------------------------------------------------------

typedef __attribute__((ext_vector_type(8))) __bf16 bf16x8;
typedef __attribute__((ext_vector_type(8))) unsigned short u16x8;
typedef __attribute__((ext_vector_type(4))) float f32x4;
typedef __attribute__((ext_vector_type(16))) float f32x16;

union U8 { u16x8 s; bf16x8 b; };
union PF { unsigned int u[4]; u16x8 s; bf16x8 b; };

__device__ __forceinline__ float bf2f(unsigned short u) {
  union { unsigned int i; float f; } c; c.i = ((unsigned int)u) << 16; return c.f;
}
__device__ __forceinline__ unsigned short f2bf(float f) {
  union { __bf16 h; unsigned short u; } c; c.h = (__bf16)f; return c.u;
}
__device__ __forceinline__ unsigned int pk2(float lo, float hi) {
  return (unsigned int)f2bf(lo) | ((unsigned int)f2bf(hi) << 16);
}

// async global->LDS, 16B per lane; LDS dest is wave-uniform base + lane*16
#define GLOAD16(gp, lp)                                                         \
  __builtin_amdgcn_global_load_lds(                                             \
      (const __attribute__((address_space(1))) void*)(gp),                      \
      (__attribute__((address_space(3))) void*)(lp), 16, 0, 0)

#define MFMA16(a, b, c) __builtin_amdgcn_mfma_f32_16x16x32_bf16((a), (b), (c), 0, 0, 0)
#define MFMA32(a, b, c) __builtin_amdgcn_mfma_f32_32x32x16_bf16((a), (b), (c), 0, 0, 0)

constexpr float ATTN_SCALE = 0.12f;
constexpr float LOG2E = 1.44269504088896340736f;
constexpr float QSCALE = ATTN_SCALE * LOG2E;  // folded into Q at fuse stage

// --------------------------- rope tables -----------------------------------
__global__ void rope_tab(float* __restrict__ ct, float* __restrict__ st) {
  const int i = blockIdx.x * 256 + threadIdx.x;
  if (i >= 4096 * 32) return;
  const int tt = i >> 5, k = i & 31;
  float cv = 1.0f, sv = 0.0f;
  if (k < 16) {
    const float af = powf(1.0f / 1024.0f, (float)k * (1.0f / 15.0f));
    const float th = (float)tt * af;
    cv = cosf(th);
    sv = sinf(th);
  }
  ct[i] = cv; st[i] = sv;
}

// --------------------------- f32 -> bf16 cast ------------------------------
__global__ void cast_f2b8(const float* __restrict__ in, unsigned short* __restrict__ out, int n8) {
  const int i = blockIdx.x * 256 + threadIdx.x;
  if (i >= n8) return;
  const float4 a = ((const float4*)in)[2 * i];
  const float4 b = ((const float4*)in)[2 * i + 1];
  u16x8 o;
  o[0] = f2bf(a.x); o[1] = f2bf(a.y); o[2] = f2bf(a.z); o[3] = f2bf(a.w);
  o[4] = f2bf(b.x); o[5] = f2bf(b.y); o[6] = f2bf(b.z); o[7] = f2bf(b.w);
  ((u16x8*)out)[i] = o;
}

// --------------------------- GEMM: C[M][N] = A[M][K] * B[N][K]^T -----------
template <int OUT_BF16>
__global__ __launch_bounds__(256) void gemm_bt(
    const unsigned short* __restrict__ A, const unsigned short* __restrict__ B,
    void* __restrict__ Cout, int M, int N, int K) {
  __shared__ unsigned short lA[128 * 32];
  __shared__ unsigned short lB[128 * 32];
  const int nbn = N >> 7;
  const int bm = blockIdx.x / nbn, bn = blockIdx.x % nbn;
  const int t = threadIdx.x;
  const int w = t >> 6, l = t & 63;
  const int g = l >> 4, c = l & 15;
  const int wr = (w >> 1) * 64, wc = (w & 1) * 64;

  const int srow = t >> 2;
  const int scol = ((t & 3) << 4) ^ ((srow & 3) << 4);  // byte col, XOR swizzle
  const char* ga = (const char*)(A + (size_t)(bm * 128 + srow) * K) + scol;
  const char* gb = (const char*)(B + (size_t)(bn * 128 + srow) * K) + scol;
  const size_t rowK2 = (size_t)64 * K * 2;
  char* la_dst = (char*)lA + t * 16;
  char* lb_dst = (char*)lB + t * 16;

  f32x4 acc[4][4] = {};

  for (int kt = 0; kt < K; kt += 32) {
    const char* gak = ga + (size_t)kt * 2;
    const char* gbk = gb + (size_t)kt * 2;
    GLOAD16(gak, la_dst);
    GLOAD16(gak + rowK2, la_dst + 4096);
    GLOAD16(gbk, lb_dst);
    GLOAD16(gbk + rowK2, lb_dst + 4096);
    __syncthreads();
    U8 af[4], bfr[4];
#pragma unroll
    for (int mi = 0; mi < 4; ++mi) {
      const int row = wr + 16 * mi + c;
      af[mi].s = *(const u16x8*)((const char*)lA + row * 64 + ((16 * g) ^ ((row & 3) << 4)));
    }
#pragma unroll
    for (int ni = 0; ni < 4; ++ni) {
      const int row = wc + 16 * ni + c;
      bfr[ni].s = *(const u16x8*)((const char*)lB + row * 64 + ((16 * g) ^ ((row & 3) << 4)));
    }
#pragma unroll
    for (int mi = 0; mi < 4; ++mi)
#pragma unroll
      for (int ni = 0; ni < 4; ++ni)
        acc[mi][ni] = MFMA16(af[mi].b, bfr[ni].b, acc[mi][ni]);
    __syncthreads();
  }
#pragma unroll
  for (int mi = 0; mi < 4; ++mi) {
#pragma unroll
    for (int ni = 0; ni < 4; ++ni) {
#pragma unroll
      for (int r = 0; r < 4; ++r) {
        const int row = bm * 128 + wr + 16 * mi + 4 * g + r;
        const int col = bn * 128 + wc + 16 * ni + c;
        const float v = acc[mi][ni][r];
        if (OUT_BF16)
          ((unsigned short*)Cout)[(size_t)row * N + col] = f2bf(v);
        else
          ((float*)Cout)[(size_t)row * N + col] = v;
      }
    }
  }
}

// --------------------------- fuse: vmix + rmsnorm + rope -------------------
__device__ __forceinline__ void load64f(const unsigned short* p, float* x) {
#pragma unroll
  for (int j = 0; j < 8; ++j) {
    const u16x8 v = *(const u16x8*)(p + 8 * j);
#pragma unroll
    for (int e = 0; e < 8; ++e) x[8 * j + e] = bf2f(v[e]);
  }
}

__device__ __forceinline__ void rmsrope_store(const float* x, const float* ct, const float* st,
                                              unsigned short* outp, float pscale) {
  float ms = 0.f;
#pragma unroll
  for (int j = 0; j < 64; ++j) ms += x[j] * x[j];
  const float sc = rsqrtf(ms * (1.0f / 64.0f) + 1.1920928955078125e-7f) * pscale;
  float y[64];
#pragma unroll
  for (int j = 0; j < 32; ++j) {
    const float cc = ct[j], ss = st[j];
    const float a = x[j] * sc, b = x[j + 32] * sc;
    y[j] = a * cc + b * ss;
    y[j + 32] = b * cc - a * ss;
  }
#pragma unroll
  for (int j = 0; j < 8; ++j) {
    u16x8 o;
#pragma unroll
    for (int e = 0; e < 8; ++e) o[e] = f2bf(y[8 * j + e]);
    *(u16x8*)(outp + 8 * j) = o;
  }
}

__global__ __launch_bounds__(256) void fuse_qkv(
    const unsigned short* __restrict__ qkv,  // [4096][3072] bf16
    const float* __restrict__ ve,            // [4096][1024]
    const float* __restrict__ lam,           // [2]
    const float* __restrict__ ct, const float* __restrict__ st,  // [4096][32]
    unsigned short* __restrict__ Qo,  // [16][4096][64]  (pre-scaled by QSCALE)
    unsigned short* __restrict__ Ko,  // [16][4096][64]
    unsigned short* __restrict__ Vo)  // [16][4096][64]
{
  const int gid = blockIdx.x * 256 + threadIdx.x;  // 65536 = 4096 t * 16 h
  const int tt = gid >> 4, h = gid & 15;
  const unsigned short* base = qkv + (size_t)tt * 3072 + h * 64;
  const float* ctp = ct + tt * 32;
  const float* stp = st + tt * 32;
  float x[64];
  load64f(base, x);
  rmsrope_store(x, ctp, stp, Qo + ((size_t)h * 4096 + tt) * 64, QSCALE);
  load64f(base + 1024, x);
  rmsrope_store(x, ctp, stp, Ko + ((size_t)h * 4096 + tt) * 64, 1.0f);
  const float l0 = lam[0], l1 = lam[1];
  const float* vp = ve + (size_t)tt * 1024 + h * 64;
  load64f(base + 2048, x);
  unsigned short* vo = Vo + ((size_t)h * 4096 + tt) * 64;
#pragma unroll
  for (int j = 0; j < 8; ++j) {
    u16x8 o;
#pragma unroll
    for (int e = 0; e < 8; ++e) o[e] = f2bf(l0 * x[8 * j + e] + l1 * vp[8 * j + e]);
    *(u16x8*)(vo + 8 * j) = o;
  }
}

// --------------------------- V transpose: [16][4096][64] -> [16][64][4096] -
__global__ __launch_bounds__(256) void transpose_v(const unsigned short* __restrict__ vin,
                                                   unsigned short* __restrict__ vout) {
  __shared__ unsigned short tile[64][72];
  const int h = (int)(blockIdx.x & 15), tb = (int)(blockIdx.x >> 4);
  const int t = threadIdx.x;
  const int r = t >> 2, c0 = (t & 3) * 16;
  const unsigned short* src = vin + ((size_t)h * 4096 + tb * 64 + r) * 64 + c0;
#pragma unroll
  for (int j = 0; j < 16; ++j) tile[c0 + j][r] = src[j];
  __syncthreads();
  unsigned short* dst = vout + ((size_t)h * 64 + r) * 4096 + tb * 64 + c0;
#pragma unroll
  for (int j = 0; j < 16; ++j) dst[j] = tile[r][c0 + j];
}

// --------------------------- flash attention (swapped 32x32) ---------------
// block = (head, 128-row q block), 4 waves x 32 q rows each. KV tiles of 64.
// Swapped QK^T: S^T = mfma_32x32x16(K, Q) -> each lane holds 32 kv values of
// ONE q row (q = lane&31; lanes l and l^32 hold complementary kv halves).
// Softmax is lane-local + one shfl_xor(32). P stays in registers: pack to
// bf16 dwords + shfl_xor(32) redistribution builds the PV B-operand directly.
// PV: O^T = mfma(V^T_frag, P^T_frag). Epilogue transposes O^T via LDS.
__global__ __launch_bounds__(256) void attn_fa(
    const unsigned short* __restrict__ Q,   // [16][4096][64] (scaled)
    const unsigned short* __restrict__ Kv,  // [16][4096][64]
    const unsigned short* __restrict__ VT,  // [16][64][4096]
    unsigned short* __restrict__ Y)         // [4096][1024]
{
  __shared__ unsigned short lk[2][64 * 64];   // K tile,  swizzled rows (128B)
  __shared__ unsigned short lv[2][64 * 64];   // V^T tile, swizzled rows

  const int h = (int)(blockIdx.x & 15);
  const int qbi = 31 - (int)(blockIdx.x >> 4);  // descending: longest first
  const int t = threadIdx.x;
  const int w = t >> 6, l = t & 63;
  const int lq = l & 31;    // this lane's q row (within wave tile)
  const int hi = l >> 5;    // kv half selector
  const int q0w = qbi * 128 + 32 * w;
  const int swz = (lq & 7) << 4;

  // Q fragments (B operand): lane holds Q[q0w+lq][16*dd + 8*hi .. +8]
  U8 qf[4];
  {
    const unsigned short* qp = Q + ((size_t)h * 4096 + q0w + lq) * 64 + 8 * hi;
#pragma unroll
    for (int dd = 0; dd < 4; ++dd) qf[dd].s = *(const u16x8*)(qp + 16 * dd);
  }

  f32x16 o0 = {}, o1 = {};   // O^T accum: d rows 0-31 / 32-63, col q = lq
  float m = -3e38f, ls = 0.0f;

  const int srow = t >> 3;                             // 0..31
  const int csw = ((t & 7) << 4) ^ ((srow & 7) << 4);  // pre-swizzled src col
  const unsigned short* kbase = Kv + (size_t)h * 4096 * 64;
  const unsigned short* vbase = VT + (size_t)h * 64 * 4096;

#define STAGE(buf, kv0)                                                          \
  do {                                                                           \
    char* lkd = (char*)lk[buf] + t * 16;                                         \
    char* lvd = (char*)lv[buf] + t * 16;                                         \
    GLOAD16((const char*)(kbase + (size_t)((kv0) + srow) * 64) + csw, lkd);      \
    GLOAD16((const char*)(kbase + (size_t)((kv0) + srow + 32) * 64) + csw,       \
            lkd + 4096);                                                         \
    GLOAD16((const char*)(vbase + (size_t)srow * 4096 + (kv0)) + csw, lvd);      \
    GLOAD16((const char*)(vbase + (size_t)(srow + 32) * 4096 + (kv0)) + csw,     \
            lvd + 4096);                                                         \
  } while (0)

  const int ntiles = 2 * qbi + 2;
  STAGE(0, 0);
  __syncthreads();
  int cur = 0;

  for (int ti = 0; ti < ntiles; ++ti) {
    const int kv0 = ti * 64;
    if (ti + 1 < ntiles) STAGE(cur ^ 1, kv0 + 64);

    if (kv0 <= q0w + 31) {  // wave-uniform: this wave has live rows here
      const char* lkc = (const char*)lk[cur];
      const char* lvc = (const char*)lv[cur];
      const bool live1 = (kv0 + 32) <= (q0w + 31);  // sub-tile st=1 live?

      // ---- S^T = K * Q^T : two 32x32 tiles over kv ----
      f32x16 s0 = {}, s1;
#pragma unroll
      for (int dd = 0; dd < 4; ++dd) {
        U8 kf;
        kf.s = *(const u16x8*)(lkc + lq * 128 + ((32 * dd + 16 * hi) ^ swz));
        s0 = MFMA32(kf.b, qf[dd].b, s0);
      }
      if (live1) {
        f32x16 z = {};
#pragma unroll
        for (int dd = 0; dd < 4; ++dd) {
          U8 kf;
          kf.s = *(const u16x8*)(lkc + 4096 + lq * 128 + ((32 * dd + 16 * hi) ^ swz));
          z = MFMA32(kf.b, qf[dd].b, z);
        }
        s1 = z;
      } else {
#pragma unroll
        for (int e = 0; e < 16; ++e) s1[e] = -3e38f;
      }

      // ---- causal mask (element kv = kv0 + 32*st + (e&3)+8*(e>>2)+4*hi) ----
      const int thr0 = q0w + lq - kv0 - 4 * hi;  // mask if kvr_base > thr
      if (kv0 + 31 > q0w) {
#pragma unroll
        for (int e = 0; e < 16; ++e) {
          const int kvr = (e & 3) + 8 * (e >> 2);
          if (kvr > thr0) s0[e] = -3e38f;
        }
      }
      if (live1 && kv0 + 63 > q0w) {
        const int thr1 = thr0 - 32;
#pragma unroll
        for (int e = 0; e < 16; ++e) {
          const int kvr = (e & 3) + 8 * (e >> 2);
          if (kvr > thr1) s1[e] = -3e38f;
        }
      }

      // ---- online softmax: all values belong to q = lq ----
      float pm = s0[0];
#pragma unroll
      for (int e = 1; e < 16; ++e) pm = fmaxf(pm, s0[e]);
#pragma unroll
      for (int e = 0; e < 16; ++e) pm = fmaxf(pm, s1[e]);
      pm = fmaxf(pm, __shfl_xor(pm, 32));
      const float mn = fmaxf(m, pm);
      float rs = 0.0f;
#pragma unroll
      for (int e = 0; e < 16; ++e) { s0[e] = exp2f(s0[e] - mn); rs += s0[e]; }
#pragma unroll
      for (int e = 0; e < 16; ++e) { s1[e] = exp2f(s1[e] - mn); rs += s1[e]; }
      rs += __shfl_xor(rs, 32);
      const float alpha = exp2f(m - mn);
      ls = ls * alpha + rs;
      m = mn;
#pragma unroll
      for (int e = 0; e < 16; ++e) { o0[e] *= alpha; o1[e] *= alpha; }

      // ---- P^T pack + redistribute + PV (O^T += V^T * P^T) ----
      // slab ks (k = kv0+16*ks..+16): B-frag dwords from tile regs 8b..8b+7
#define DO_SLAB(SV, B, KS)                                                       \
  do {                                                                           \
    const unsigned int ua = pk2(SV[8 * (B) + 0], SV[8 * (B) + 1]);               \
    const unsigned int ub = pk2(SV[8 * (B) + 2], SV[8 * (B) + 3]);               \
    const unsigned int uc = pk2(SV[8 * (B) + 4], SV[8 * (B) + 5]);               \
    const unsigned int ud = pk2(SV[8 * (B) + 6], SV[8 * (B) + 7]);               \
    const unsigned int sa = (unsigned int)__shfl_xor((int)ua, 32);               \
    const unsigned int sb = (unsigned int)__shfl_xor((int)ub, 32);               \
    const unsigned int sc = (unsigned int)__shfl_xor((int)uc, 32);               \
    const unsigned int sd = (unsigned int)__shfl_xor((int)ud, 32);               \
    PF pf;                                                                       \
    pf.u[0] = hi ? sc : ua;                                                      \
    pf.u[1] = hi ? sd : ub;                                                      \
    pf.u[2] = hi ? uc : sa;                                                      \
    pf.u[3] = hi ? ud : sb;                                                      \
    U8 vf0, vf1;                                                                 \
    const int vb = (32 * (KS) + 16 * hi) ^ swz;                                  \
    vf0.s = *(const u16x8*)(lvc + lq * 128 + vb);                                \
    vf1.s = *(const u16x8*)(lvc + 4096 + lq * 128 + vb);                         \
    o0 = MFMA32(vf0.b, pf.b, o0);                                                \
    o1 = MFMA32(vf1.b, pf.b, o1);                                                \
  } while (0)

      DO_SLAB(s0, 0, 0);
      DO_SLAB(s0, 1, 1);
      if (live1) {
        DO_SLAB(s1, 0, 2);
        DO_SLAB(s1, 1, 3);
      }
#undef DO_SLAB
    }
    __syncthreads();
    cur ^= 1;
  }
#undef STAGE

  // ---- epilogue: y = O^T / ls; transpose via per-wave LDS; coalesced store
  const float inv = 1.0f / ls;
  char* ep = (char*)lk + w * 4096;  // 32 rows(q) x 128B(d), swizzled
#pragma unroll
  for (int dt = 0; dt < 2; ++dt) {
#pragma unroll
    for (int rr = 0; rr < 4; ++rr) {
      const float a0 = (dt ? o1[4 * rr + 0] : o0[4 * rr + 0]) * inv;
      const float a1 = (dt ? o1[4 * rr + 1] : o0[4 * rr + 1]) * inv;
      const float a2 = (dt ? o1[4 * rr + 2] : o0[4 * rr + 2]) * inv;
      const float a3 = (dt ? o1[4 * rr + 3] : o0[4 * rr + 3]) * inv;
      const unsigned long long v =
          (unsigned long long)pk2(a0, a1) | ((unsigned long long)pk2(a2, a3) << 32);
      const int blk = 4 * dt + rr;
      *(unsigned long long*)(ep + lq * 128 + ((blk << 4) ^ swz) + 8 * hi) = v;
    }
  }
  __syncthreads();
#pragma unroll
  for (int i = 0; i < 4; ++i) {
    const int qq = 8 * i + (l >> 3);
    const u16x8 vv =
        *(const u16x8*)(ep + qq * 128 + (((l & 7) << 4) ^ ((qq & 7) << 4)));
    *(u16x8*)(Y + (size_t)(q0w + qq) * 1024 + h * 64 + (l & 7) * 8) = vv;
  }
}

// --------------------------- launcher --------------------------------------
extern "C" void kernel_launch(void* const* d_in, const int* in_sizes, int n_in,
                              void* d_out, int out_size, void* d_ws, size_t ws_size,
                              hipStream_t stream) {
  const float* x   = (const float*)d_in[0];
  const float* ve  = (const float*)d_in[1];
  const float* qw  = (const float*)d_in[2];
  const float* lam = (const float*)d_in[3];
  const float* pw  = (const float*)d_in[4];
  float* out = (float*)d_out;

  unsigned short* ws = (unsigned short*)d_ws;
  unsigned short* x_bf  = ws;                                // 4096*1024
  unsigned short* wqkv  = x_bf + (size_t)4096 * 1024;        // 3072*1024
  unsigned short* wproj = wqkv + (size_t)3072 * 1024;        // 1024*1024
  unsigned short* qkv   = wproj + (size_t)1024 * 1024;       // 4096*3072
  unsigned short* Qr    = qkv + (size_t)4096 * 3072;         // 16*4096*64
  unsigned short* Kr    = Qr + (size_t)4096 * 1024;
  unsigned short* Vm    = Kr + (size_t)4096 * 1024;
  unsigned short* VTt   = Vm + (size_t)4096 * 1024;
  unsigned short* Yb    = VTt + (size_t)4096 * 1024;
  float* ct = (float*)(Yb + (size_t)4096 * 1024);            // 4096*32
  float* st = ct + 4096 * 32;

  rope_tab<<<512, 256, 0, stream>>>(ct, st);
  cast_f2b8<<<2048, 256, 0, stream>>>(x, x_bf, 524288);
  cast_f2b8<<<1536, 256, 0, stream>>>(qw, wqkv, 393216);
  cast_f2b8<<<512, 256, 0, stream>>>(pw, wproj, 131072);
  gemm_bt<1><<<768, 256, 0, stream>>>(x_bf, wqkv, (void*)qkv, 4096, 3072, 1024);
  fuse_qkv<<<256, 256, 0, stream>>>(qkv, ve, lam, ct, st, Qr, Kr, Vm);
  transpose_v<<<1024, 256, 0, stream>>>(Vm, VTt);
  attn_fa<<<512, 256, 0, stream>>>(Qr, Kr, VTt, Yb);
  gemm_bt<0><<<256, 256, 0, stream>>>(Yb, wproj, (void*)out, 4096, 1024, 1024);
}